// Round 7
// baseline (657.444 us; speedup 1.0000x reference)
//
#include <hip/hip_runtime.h>
#include <math.h>

#define NTOT 33554432
#define CS 64
#define REF 16
#define HID 64
#define NC (NTOT / CS)

typedef float fx4 __attribute__((ext_vector_type(4)));  // nontemporal-builtin-compatible

// ws layout (floats):
//   [0,1024)     ga[j][k]    = w_g1[j][k] + w_g1[j][32+k]      (ea coefficient)
//   [1024,2048)  gb[j][k]    = w_g1[j][16+k] - w_g1[j][32+k]   (eb coefficient)
//   [2048,3072)  gp[j][k]    = w_g1[j][48+k]                   (ea*eb coefficient)
//   [3072,4096)  wc1c[j][k]  = w_c1[j][k] + w_c1[j][32+k]      (enc coefficient)
//   [4096,4160)  refc_p[j]   = b_c1[j] + sum_k ref_policy[k]*(w_c1[j][16+k]-w_c1[j][32+k])
//   [4160,4224)  refc_m[j]   = same with ref_meta
//   [4224,5248)  w_encT[k][j] = w_enc[j][k]   (contiguous 64B per k -> s_load_dwordx4 runs)
#define WS_FLOATS 5248

#if defined(__has_builtin)
#if __has_builtin(__builtin_amdgcn_rcpf)
#define FAST_RCP(x) __builtin_amdgcn_rcpf(x)
#endif
#endif
#ifndef FAST_RCP
#define FAST_RCP(x) (1.0f / (x))
#endif

__device__ __forceinline__ float fast_tanh(float x) {
  // tanh(x) = 1 - 2/(exp(2x)+1); exp overflow/underflow saturates correctly.
  float e = __expf(2.0f * x);
  return 1.0f - 2.0f * FAST_RCP(e + 1.0f);
}

__device__ __forceinline__ float get4(const float4& v, int c) {
  return c == 0 ? v.x : c == 1 ? v.y : c == 2 ? v.z : v.w;
}

// 64 compile-time-indexed invocations: h lives in 64 NAMED scalars, never an
// alloca. (R1-R5: float h[64] was never promoted to registers -> 128 MB
// scratch stores + ~1.5 GB scratch re-fetch per launch; promote-alloca's
// threshold is between 16 and 64 elements.)
#define REPEAT64(OP) \
  OP(0) OP(1) OP(2) OP(3) OP(4) OP(5) OP(6) OP(7) \
  OP(8) OP(9) OP(10) OP(11) OP(12) OP(13) OP(14) OP(15) \
  OP(16) OP(17) OP(18) OP(19) OP(20) OP(21) OP(22) OP(23) \
  OP(24) OP(25) OP(26) OP(27) OP(28) OP(29) OP(30) OP(31) \
  OP(32) OP(33) OP(34) OP(35) OP(36) OP(37) OP(38) OP(39) \
  OP(40) OP(41) OP(42) OP(43) OP(44) OP(45) OP(46) OP(47) \
  OP(48) OP(49) OP(50) OP(51) OP(52) OP(53) OP(54) OP(55) \
  OP(56) OP(57) OP(58) OP(59) OP(60) OP(61) OP(62) OP(63)

__global__ void setup_fold_kernel(const float* __restrict__ w_g1,
                                  const float* __restrict__ w_c1,
                                  const float* __restrict__ b_c1,
                                  const float* __restrict__ w_enc,
                                  const float* __restrict__ ref_p,
                                  const float* __restrict__ ref_m,
                                  float* __restrict__ ws) {
  const int t = threadIdx.x;  // single block of 256
  for (int idx = t; idx < 1024; idx += 256) {
    const int j = idx >> 4, k = idx & 15;
    ws[idx]        = w_g1[j * 64 + k] + w_g1[j * 64 + 32 + k];
    ws[1024 + idx] = w_g1[j * 64 + 16 + k] - w_g1[j * 64 + 32 + k];
    ws[2048 + idx] = w_g1[j * 64 + 48 + k];
    ws[3072 + idx] = w_c1[j * 48 + k] + w_c1[j * 48 + 32 + k];
    // w_encT: idx = k*16 + j2  (k in [0,64), j2 in [0,16))
    ws[4224 + idx] = w_enc[(idx & 15) * 64 + (idx >> 4)];
  }
  if (t < 64) {
    float sp = b_c1[t], sm = b_c1[t];
    for (int k = 0; k < REF; ++k) {
      const float wd = w_c1[t * 48 + 16 + k] - w_c1[t * 48 + 32 + k];
      sp += ref_p[k] * wd;
      sm += ref_m[k] * wd;
    }
    ws[4096 + t] = sp;
    ws[4160 + t] = sm;
  }
}

__device__ __forceinline__ float hcalc(int j, bool policy,
                                       const float* __restrict__ ws,
                                       const float* enc) {
  float acc = policy ? ws[4096 + j] : ws[4160 + j];
  const float* wc = ws + 3072 + j * REF;  // contiguous, wave-uniform -> s_load
#pragma unroll
  for (int k = 0; k < REF; ++k) acc = fmaf(enc[k], wc[k], acc);
  return fast_tanh(acc);
}

__global__ void __launch_bounds__(256, 2) dual_mutate_kernel(
    const float* __restrict__ A, const float* __restrict__ B,
    const int* __restrict__ coords, const float* __restrict__ noise,
    const float* __restrict__ b_enc, const float* __restrict__ w_c2,
    const float* __restrict__ b_c2, const float* __restrict__ b_g1,
    const float* __restrict__ w_g2, const float* __restrict__ b_g2,
    const float* __restrict__ cs_p, const float* __restrict__ cs_m,
    const float* __restrict__ es_p, const float* __restrict__ es_m,
    const float* __restrict__ ws, float* __restrict__ out) {
  const int chunk = blockIdx.x * blockDim.x + threadIdx.x;
  if (chunk >= NC) return;
  const size_t off = (size_t)chunk * CS;
  const float* ap = A + off;
  const float* bp = B + off;

  // ---------------- Phase A: pre-activations za, zb -------------------------
  float za[REF], zb[REF];
#pragma unroll
  for (int j = 0; j < REF; ++j) {
    const float bj = b_enc[j];
    za[j] = bj;
    zb[j] = bj;
  }
#pragma unroll 4
  for (int k4 = 0; k4 < CS / 4; ++k4) {
    const float4 a4 = *reinterpret_cast<const float4*>(ap + 4 * k4);
    const float4 b4 = *reinterpret_cast<const float4*>(bp + 4 * k4);
#pragma unroll
    for (int c = 0; c < 4; ++c) {
      const float av = get4(a4, c);
      const float bv = get4(b4, c);
      const int k = 4 * k4 + c;
      const float* wT = ws + 4224 + k * REF;  // contiguous, wave-uniform -> s_load
#pragma unroll
      for (int j = 0; j < REF; ++j) {
        za[j] = fmaf(av, wT[j], za[j]);
        zb[j] = fmaf(bv, wT[j], zb[j]);
      }
    }
  }

  // ---------------- Gate: alpha = sigmoid(l0 - l1) --------------------------
  float ea[REF], eb[REF], pp[REF];
#pragma unroll
  for (int j = 0; j < REF; ++j) {
    ea[j] = fast_tanh(za[j]);
    eb[j] = fast_tanh(zb[j]);
    pp[j] = ea[j] * eb[j];
  }
  float l0 = b_g2[0], l1 = b_g2[1];
#pragma unroll 2
  for (int j = 0; j < HID; ++j) {
    float acc = b_g1[j];
#pragma unroll
    for (int k = 0; k < REF; ++k) {
      acc = fmaf(ea[k], ws[j * REF + k], acc);
      acc = fmaf(eb[k], ws[1024 + j * REF + k], acc);
      acc = fmaf(pp[k], ws[2048 + j * REF + k], acc);
    }
    const float hh = fast_tanh(acc);
    l0 = fmaf(w_g2[j], hh, l0);
    l1 = fmaf(w_g2[HID + j], hh, l1);
  }
  const float alpha = FAST_RCP(1.0f + __expf(l1 - l0));

  // ---------------- enc(base) via linearity: z = a*za + (1-a)*zb ------------
  const int split = coords[0];
  const bool policy = (chunk * CS) < split;
  float enc[REF];
#pragma unroll
  for (int j = 0; j < REF; ++j)
    enc[j] = fast_tanh(fmaf(alpha, za[j] - zb[j], zb[j]));

  // ---------------- h0..h63 as named scalars (forced register residency) ----
#define DECL_H(j) float h##j;
  REPEAT64(DECL_H)
#undef DECL_H
#define COMP_H(j) h##j = hcalc(j, policy, ws, enc);
  REPEAT64(COMP_H)
#undef COMP_H

  // ---------------- Output: recompute base, corr on the fly -----------------
  const float csv = policy ? cs_p[0] : cs_m[0];
  const float esv = policy ? es_p[0] : es_m[0];
  const float* np_ = noise + off;
  float* op = out + off;
#pragma unroll 1
  for (int k4 = 0; k4 < CS / 4; ++k4) {
    const float4 a4 = *reinterpret_cast<const float4*>(ap + 4 * k4);
    const float4 b4 = *reinterpret_cast<const float4*>(bp + 4 * k4);
    const fx4 n4 = __builtin_nontemporal_load(
        reinterpret_cast<const fx4*>(np_ + 4 * k4));
    fx4 o;
#pragma unroll
    for (int c = 0; c < 4; ++c) {
      const int i = 4 * k4 + c;  // wave-uniform row of w_c2
      const float av = get4(a4, c);
      const float bv = get4(b4, c);
      const float bb = fmaf(alpha, av - bv, bv);  // alpha*a + (1-alpha)*b
      float corr = b_c2[i];
      const float* wrow = w_c2 + (size_t)i * HID;  // wave-uniform -> s_load
#define ACC_C(j) corr = fmaf(h##j, wrow[j], corr);
      REPEAT64(ACC_C)
#undef ACC_C
      float cv = fast_tanh(corr) * csv;
      cv = fminf(fmaxf(cv, -0.1f), 0.1f);
      o[c] = bb + cv + n4[c] * esv;
    }
    __builtin_nontemporal_store(o, reinterpret_cast<fx4*>(op + 4 * k4));
  }
}

extern "C" void kernel_launch(void* const* d_in, const int* in_sizes, int n_in,
                              void* d_out, int out_size, void* d_ws, size_t ws_size,
                              hipStream_t stream) {
  const float* A     = (const float*)d_in[0];
  const float* B     = (const float*)d_in[1];
  const int*   coord = (const int*)d_in[2];
  const float* noise = (const float*)d_in[3];
  const float* w_enc = (const float*)d_in[4];
  const float* b_enc = (const float*)d_in[5];
  const float* w_c1  = (const float*)d_in[6];
  const float* b_c1  = (const float*)d_in[7];
  const float* w_c2  = (const float*)d_in[8];
  const float* b_c2  = (const float*)d_in[9];
  const float* w_g1  = (const float*)d_in[10];
  const float* b_g1  = (const float*)d_in[11];
  const float* w_g2  = (const float*)d_in[12];
  const float* b_g2  = (const float*)d_in[13];
  const float* ref_p = (const float*)d_in[14];
  const float* ref_m = (const float*)d_in[15];
  const float* cs_p  = (const float*)d_in[16];
  const float* cs_m  = (const float*)d_in[17];
  const float* es_p  = (const float*)d_in[18];
  const float* es_m  = (const float*)d_in[19];
  float* out = (float*)d_out;
  float* ws  = (float*)d_ws;

  setup_fold_kernel<<<1, 256, 0, stream>>>(w_g1, w_c1, b_c1, w_enc, ref_p, ref_m, ws);

  const int blocks = NC / 256;
  dual_mutate_kernel<<<blocks, 256, 0, stream>>>(
      A, B, coord, noise, b_enc, w_c2, b_c2, b_g1,
      w_g2, b_g2, cs_p, cs_m, es_p, es_m, ws, out);
}

// Round 8
// 494.586 us; speedup vs baseline: 1.3293x; 1.3293x over previous
//
#include <hip/hip_runtime.h>
#include <math.h>

#define NTOT 33554432
#define CS 64
#define REF 16
#define HID 64
#define NC (NTOT / CS)

typedef float fx4 __attribute__((ext_vector_type(4)));  // nontemporal-builtin-compatible

// ws layout (floats):
//   [0,1024)     ga[j][k]    = w_g1[j][k] + w_g1[j][32+k]      (ea coefficient)
//   [1024,2048)  gb[j][k]    = w_g1[j][16+k] - w_g1[j][32+k]   (eb coefficient)
//   [2048,3072)  gp[j][k]    = w_g1[j][48+k]                   (ea*eb coefficient)
//   [3072,4096)  wc1c[j][k]  = w_c1[j][k] + w_c1[j][32+k]      (enc coefficient)
//   [4096,4160)  refc_p[j]   = b_c1[j] + sum_k ref_policy[k]*(w_c1[j][16+k]-w_c1[j][32+k])
//   [4160,4224)  refc_m[j]   = same with ref_meta
//   [4224,8320)  w_c2T[j][i] = w_c2[i][j]     (row j contiguous -> s_load runs)
//   [8320,9344)  w_encT[k][j] = w_enc[j][k]   (row k contiguous)
//   [9344,9408)  dw[j]       = w_g2[0][j] - w_g2[1][j]
//   [9408]       bdiff       = b_g2[0] - b_g2[1]
#define WS_FLOATS 9409

#if defined(__has_builtin)
#if __has_builtin(__builtin_amdgcn_rcpf)
#define FAST_RCP(x) __builtin_amdgcn_rcpf(x)
#endif
#endif
#ifndef FAST_RCP
#define FAST_RCP(x) (1.0f / (x))
#endif

__device__ __forceinline__ float fast_tanh(float x) {
  // tanh(x) = 1 - 2/(exp(2x)+1); exp overflow/underflow saturates correctly.
  float e = __expf(2.0f * x);
  return 1.0f - 2.0f * FAST_RCP(e + 1.0f);
}

__device__ __forceinline__ float get4(const float4& v, int c) {
  return c == 0 ? v.x : c == 1 ? v.y : c == 2 ? v.z : v.w;
}

__global__ void setup_fold_kernel(const float* __restrict__ w_g1,
                                  const float* __restrict__ w_c1,
                                  const float* __restrict__ b_c1,
                                  const float* __restrict__ w_enc,
                                  const float* __restrict__ w_c2,
                                  const float* __restrict__ w_g2,
                                  const float* __restrict__ b_g2,
                                  const float* __restrict__ ref_p,
                                  const float* __restrict__ ref_m,
                                  float* __restrict__ ws) {
  const int t = threadIdx.x;  // single block of 256
  for (int idx = t; idx < 1024; idx += 256) {
    const int j = idx >> 4, k = idx & 15;
    ws[idx]        = w_g1[j * 64 + k] + w_g1[j * 64 + 32 + k];
    ws[1024 + idx] = w_g1[j * 64 + 16 + k] - w_g1[j * 64 + 32 + k];
    ws[2048 + idx] = w_g1[j * 64 + 48 + k];
    ws[3072 + idx] = w_c1[j * 48 + k] + w_c1[j * 48 + 32 + k];
    // w_encT: idx = k2*16 + j2  (k2 in [0,64), j2 in [0,16))
    ws[8320 + idx] = w_enc[(idx & 15) * 64 + (idx >> 4)];
  }
  for (int idx = t; idx < 4096; idx += 256) {
    const int j = idx >> 6, i = idx & 63;
    ws[4224 + idx] = w_c2[i * 64 + j];
  }
  if (t < 64) {
    float sp = b_c1[t], sm = b_c1[t];
    for (int k = 0; k < REF; ++k) {
      const float wd = w_c1[t * 48 + 16 + k] - w_c1[t * 48 + 32 + k];
      sp += ref_p[k] * wd;
      sm += ref_m[k] * wd;
    }
    ws[4096 + t] = sp;
    ws[4160 + t] = sm;
    ws[9344 + t] = w_g2[t] - w_g2[64 + t];
  }
  if (t == 0) ws[9408] = b_g2[0] - b_g2[1];
}

__global__ void __launch_bounds__(256) dual_mutate_kernel(
    const float* __restrict__ A, const float* __restrict__ B,
    const int* __restrict__ coords, const float* __restrict__ noise,
    const float* __restrict__ b_enc, const float* __restrict__ b_c2,
    const float* __restrict__ b_g1,
    const float* __restrict__ cs_p, const float* __restrict__ cs_m,
    const float* __restrict__ es_p, const float* __restrict__ es_m,
    const float* __restrict__ ws, float* __restrict__ out) {
  const int chunk = blockIdx.x * blockDim.x + threadIdx.x;
  if (chunk >= NC) return;
  const size_t off = (size_t)chunk * CS;
  const float* ap = A + off;
  const float* bp = B + off;

  // ---------------- Phase A: pre-activations za, zb -------------------------
  float za[REF], zb[REF];
#pragma unroll
  for (int j = 0; j < REF; ++j) {
    const float bj = b_enc[j];
    za[j] = bj;
    zb[j] = bj;
  }
#pragma unroll 4
  for (int k4 = 0; k4 < CS / 4; ++k4) {
    const float4 a4 = *reinterpret_cast<const float4*>(ap + 4 * k4);
    const float4 b4 = *reinterpret_cast<const float4*>(bp + 4 * k4);
#pragma unroll
    for (int c = 0; c < 4; ++c) {
      const float av = get4(a4, c);
      const float bv = get4(b4, c);
      const int k = 4 * k4 + c;
      const float* wT = ws + 8320 + k * REF;  // contiguous, wave-uniform -> s_load
#pragma unroll
      for (int j = 0; j < REF; ++j) {
        za[j] = fmaf(av, wT[j], za[j]);
        zb[j] = fmaf(bv, wT[j], zb[j]);
      }
    }
  }

  // ---------------- Gate: single folded logit -------------------------------
  float ea[REF], eb[REF], pp[REF];
#pragma unroll
  for (int j = 0; j < REF; ++j) {
    ea[j] = fast_tanh(za[j]);
    eb[j] = fast_tanh(zb[j]);
    pp[j] = ea[j] * eb[j];
  }
  float logit = ws[9408];
#pragma unroll 2
  for (int j = 0; j < HID; ++j) {
    float acc = b_g1[j];
#pragma unroll
    for (int k = 0; k < REF; ++k) {
      acc = fmaf(ea[k], ws[j * REF + k], acc);
      acc = fmaf(eb[k], ws[1024 + j * REF + k], acc);
      acc = fmaf(pp[k], ws[2048 + j * REF + k], acc);
    }
    logit = fmaf(ws[9344 + j], fast_tanh(acc), logit);
  }
  const float alpha = FAST_RCP(1.0f + __expf(-logit));

  // ---------------- enc(base) via linearity: z = a*za + (1-a)*zb ------------
  const int split = coords[0];
  const bool policy = (chunk * CS) < split;
  float enc[REF];
#pragma unroll
  for (int j = 0; j < REF; ++j)
    enc[j] = fast_tanh(fmaf(alpha, za[j] - zb[j], zb[j]));

  const float csv = policy ? cs_p[0] : cs_m[0];
  const float esv = policy ? es_p[0] : es_m[0];
  const float* np_ = noise + off;
  float* op = out + off;

  // ---------------- Output: 2 strips of 32; h recomputed per strip ----------
  // Max live state: corrA[16]+corrB[16]+enc[16]+temps (~70) -> no 64-wide
  // long-lived set anywhere (R1-R6's spill source).
#pragma unroll 1
  for (int s = 0; s < 2; ++s) {
    float corrA[16], corrB[16];
#pragma unroll
    for (int ii = 0; ii < 16; ++ii) {
      corrA[ii] = b_c2[s * 32 + ii];
      corrB[ii] = b_c2[s * 32 + 16 + ii];
    }
#pragma unroll 2
    for (int j = 0; j < HID; ++j) {
      const float c0p = ws[4096 + j];           // s_load
      const float c0m = ws[4160 + j];           // s_load
      float acc = policy ? c0p : c0m;           // v_cndmask
      const float* wc = ws + 3072 + j * REF;    // contiguous, wave-uniform
#pragma unroll
      for (int k = 0; k < REF; ++k) acc = fmaf(enc[k], wc[k], acc);
      const float hj = fast_tanh(acc);
      const float* w2 = ws + 4224 + j * HID + s * 32;  // wave-uniform row
#pragma unroll
      for (int ii = 0; ii < 16; ++ii) corrA[ii] = fmaf(hj, w2[ii], corrA[ii]);
#pragma unroll
      for (int ii = 0; ii < 16; ++ii) corrB[ii] = fmaf(hj, w2[16 + ii], corrB[ii]);
    }
    // Strip epilogue: recompute base from (L1/L2-hot) a,b; add corr + noise.
#pragma unroll
    for (int q = 0; q < 8; ++q) {
      const int i0 = s * 32 + 4 * q;
      const float4 a4 = *reinterpret_cast<const float4*>(ap + i0);
      const float4 b4 = *reinterpret_cast<const float4*>(bp + i0);
      const fx4 n4 = __builtin_nontemporal_load(
          reinterpret_cast<const fx4*>(np_ + i0));
      fx4 o;
#pragma unroll
      for (int c = 0; c < 4; ++c) {
        const float av = get4(a4, c);
        const float bv = get4(b4, c);
        const float bb = fmaf(alpha, av - bv, bv);  // alpha*a + (1-alpha)*b
        const float cr = (q < 4) ? ((const float*)corrA)[(4 * q + c) & 15]
                                 : ((const float*)corrB)[(4 * q + c) & 15];
        float cv = fast_tanh(cr) * csv;
        cv = fminf(fmaxf(cv, -0.1f), 0.1f);
        o[c] = bb + cv + n4[c] * esv;
      }
      __builtin_nontemporal_store(o, reinterpret_cast<fx4*>(op + i0));
    }
  }
}

extern "C" void kernel_launch(void* const* d_in, const int* in_sizes, int n_in,
                              void* d_out, int out_size, void* d_ws, size_t ws_size,
                              hipStream_t stream) {
  const float* A     = (const float*)d_in[0];
  const float* B     = (const float*)d_in[1];
  const int*   coord = (const int*)d_in[2];
  const float* noise = (const float*)d_in[3];
  const float* w_enc = (const float*)d_in[4];
  const float* b_enc = (const float*)d_in[5];
  const float* w_c1  = (const float*)d_in[6];
  const float* b_c1  = (const float*)d_in[7];
  const float* w_c2  = (const float*)d_in[8];
  const float* b_c2  = (const float*)d_in[9];
  const float* w_g1  = (const float*)d_in[10];
  const float* b_g1  = (const float*)d_in[11];
  const float* w_g2  = (const float*)d_in[12];
  const float* b_g2  = (const float*)d_in[13];
  const float* ref_p = (const float*)d_in[14];
  const float* ref_m = (const float*)d_in[15];
  const float* cs_p  = (const float*)d_in[16];
  const float* cs_m  = (const float*)d_in[17];
  const float* es_p  = (const float*)d_in[18];
  const float* es_m  = (const float*)d_in[19];
  float* out = (float*)d_out;
  float* ws  = (float*)d_ws;

  setup_fold_kernel<<<1, 256, 0, stream>>>(w_g1, w_c1, b_c1, w_enc, w_c2,
                                           w_g2, b_g2, ref_p, ref_m, ws);

  const int blocks = NC / 256;
  dual_mutate_kernel<<<blocks, 256, 0, stream>>>(
      A, B, coord, noise, b_enc, b_c2, b_g1,
      cs_p, cs_m, es_p, es_m, ws, out);
}

// Round 9
// 471.484 us; speedup vs baseline: 1.3944x; 1.0490x over previous
//
#include <hip/hip_runtime.h>
#include <math.h>

#define NTOT 33554432
#define CS 64
#define REF 16
#define HID 64
#define NC (NTOT / CS)

typedef float fx4 __attribute__((ext_vector_type(4)));     // nontemporal-compatible
typedef unsigned ux4 __attribute__((ext_vector_type(4)));  // LDS b128 payloads

// ws layout (floats):
//   [0,1024)     ga[j][k]    = w_g1[j][k] + w_g1[j][32+k]      (ea coefficient)
//   [1024,2048)  gb[j][k]    = w_g1[j][16+k] - w_g1[j][32+k]   (eb coefficient)
//   [2048,3072)  gp[j][k]    = w_g1[j][48+k]                   (ea*eb coefficient)
//   [3072,4096)  wc1c[j][k]  = w_c1[j][k] + w_c1[j][32+k]      (enc coefficient)
//   [4096,4160)  refc_p[j]   = b_c1[j] + sum_k ref_policy[k]*(w_c1[j][16+k]-w_c1[j][32+k])
//   [4160,4224)  refc_m[j]   = same with ref_meta
//   [4224,8320)  w_c2T[j][i] = w_c2[i][j]     (row j contiguous -> s_load runs)
//   [8320,9344)  w_encT[k][j] = w_enc[j][k]   (row k contiguous)
//   [9344,9408)  dw[j]       = w_g2[0][j] - w_g2[1][j]
//   [9408]       bdiff       = b_g2[0] - b_g2[1]
#define WS_FLOATS 9409

#if defined(__has_builtin)
#if __has_builtin(__builtin_amdgcn_rcpf)
#define FAST_RCP(x) __builtin_amdgcn_rcpf(x)
#endif
#endif
#ifndef FAST_RCP
#define FAST_RCP(x) (1.0f / (x))
#endif

__device__ __forceinline__ float fast_tanh(float x) {
  float e = __expf(2.0f * x);
  return 1.0f - 2.0f * FAST_RCP(e + 1.0f);
}

__device__ __forceinline__ float get4(const float4& v, int c) {
  return c == 0 ? v.x : c == 1 ? v.y : c == 2 ? v.z : v.w;
}

// bf16x2 pack (round-half-up) / unpack. Operands here are bounded (|x| < 40),
// so the +0x8000 rounding can't overflow into inf/nan territory.
__device__ __forceinline__ unsigned bpack2(float lo, float hi) {
  unsigned ul = __builtin_bit_cast(unsigned, lo);
  unsigned uh = __builtin_bit_cast(unsigned, hi);
  return ((ul + 0x8000u) >> 16) | ((uh + 0x8000u) & 0xFFFF0000u);
}
__device__ __forceinline__ float blo(unsigned p) {
  return __builtin_bit_cast(float, p << 16);
}
__device__ __forceinline__ float bhi(unsigned p) {
  return __builtin_bit_cast(float, p & 0xFFFF0000u);
}

__global__ void setup_fold_kernel(const float* __restrict__ w_g1,
                                  const float* __restrict__ w_c1,
                                  const float* __restrict__ b_c1,
                                  const float* __restrict__ w_enc,
                                  const float* __restrict__ w_c2,
                                  const float* __restrict__ w_g2,
                                  const float* __restrict__ b_g2,
                                  const float* __restrict__ ref_p,
                                  const float* __restrict__ ref_m,
                                  float* __restrict__ ws) {
  const int t = threadIdx.x;  // single block of 256
  for (int idx = t; idx < 1024; idx += 256) {
    const int j = idx >> 4, k = idx & 15;
    ws[idx]        = w_g1[j * 64 + k] + w_g1[j * 64 + 32 + k];
    ws[1024 + idx] = w_g1[j * 64 + 16 + k] - w_g1[j * 64 + 32 + k];
    ws[2048 + idx] = w_g1[j * 64 + 48 + k];
    ws[3072 + idx] = w_c1[j * 48 + k] + w_c1[j * 48 + 32 + k];
    ws[8320 + idx] = w_enc[(idx & 15) * 64 + (idx >> 4)];
  }
  for (int idx = t; idx < 4096; idx += 256) {
    const int j = idx >> 6, i = idx & 63;
    ws[4224 + idx] = w_c2[i * 64 + j];
  }
  if (t < 64) {
    float sp = b_c1[t], sm = b_c1[t];
    for (int k = 0; k < REF; ++k) {
      const float wd = w_c1[t * 48 + 16 + k] - w_c1[t * 48 + 32 + k];
      sp += ref_p[k] * wd;
      sm += ref_m[k] * wd;
    }
    ws[4096 + t] = sp;
    ws[4160 + t] = sm;
    ws[9344 + t] = w_g2[t] - w_g2[64 + t];
  }
  if (t == 0) ws[9408] = b_g2[0] - b_g2[1];
}

// Per-thread LDS stash: stride 36 u32 (144 B, b128-aligned).
//   u32 [0,16): first zpk (za,zb bf16 pairs), later overwritten by hpk
//   u32 [0,32): hpk (h as 64 bf16) -- zpk is dead by then
// Every long-lived register array is <=16 wide; the 32-64 wide state that
// R0-R7 kept spilling (za/zb across gate, h/corr across strips) lives here.
__global__ void __launch_bounds__(256) dual_mutate_kernel(
    const float* __restrict__ A, const float* __restrict__ B,
    const int* __restrict__ coords, const float* __restrict__ noise,
    const float* __restrict__ b_enc, const float* __restrict__ b_c2,
    const float* __restrict__ b_g1,
    const float* __restrict__ cs_p, const float* __restrict__ cs_m,
    const float* __restrict__ es_p, const float* __restrict__ es_m,
    const float* __restrict__ ws, float* __restrict__ out) {
  __shared__ unsigned lds_u[256 * 36];
  const int tid = threadIdx.x;
  unsigned* row = lds_u + tid * 36;  // private; no barriers needed

  const int chunk = blockIdx.x * blockDim.x + tid;
  if (chunk >= NC) return;
  const size_t off = (size_t)chunk * CS;
  const float* ap = A + off;
  const float* bp = B + off;

  // ---------------- Phase A: pre-activations za, zb -------------------------
  float za[REF], zb[REF];
#pragma unroll
  for (int j = 0; j < REF; ++j) {
    const float bj = b_enc[j];
    za[j] = bj;
    zb[j] = bj;
  }
#pragma unroll 4
  for (int k4 = 0; k4 < CS / 4; ++k4) {
    const float4 a4 = *reinterpret_cast<const float4*>(ap + 4 * k4);
    const float4 b4 = *reinterpret_cast<const float4*>(bp + 4 * k4);
#pragma unroll
    for (int c = 0; c < 4; ++c) {
      const float av = get4(a4, c);
      const float bv = get4(b4, c);
      const int k = 4 * k4 + c;
      const float* wT = ws + 8320 + k * REF;  // contiguous, wave-uniform
#pragma unroll
      for (int j = 0; j < REF; ++j) {
        za[j] = fmaf(av, wT[j], za[j]);
        zb[j] = fmaf(bv, wT[j], zb[j]);
      }
    }
  }

  // Stash (za,zb) as bf16 pairs in LDS; then za/zb die into ea/eb.
#pragma unroll
  for (int q = 0; q < 4; ++q) {
    ux4 p;
#pragma unroll
    for (int m = 0; m < 4; ++m) p[m] = bpack2(za[4 * q + m], zb[4 * q + m]);
    *reinterpret_cast<ux4*>(row + 4 * q) = p;
  }
  float ea[REF], eb[REF];
#pragma unroll
  for (int j = 0; j < REF; ++j) {
    ea[j] = fast_tanh(za[j]);
    eb[j] = fast_tanh(zb[j]);
  }

  // ---------------- Gate: single folded logit (pp recomputed per j) ---------
  float logit = ws[9408];
#pragma unroll 2
  for (int j = 0; j < HID; ++j) {
    float acc = b_g1[j];
#pragma unroll
    for (int k = 0; k < REF; ++k) {
      acc = fmaf(ea[k], ws[j * REF + k], acc);
      acc = fmaf(eb[k], ws[1024 + j * REF + k], acc);
      acc = fmaf(ea[k] * eb[k], ws[2048 + j * REF + k], acc);
    }
    logit = fmaf(ws[9344 + j], fast_tanh(acc), logit);
  }
  const float alpha = FAST_RCP(1.0f + __expf(-logit));

  // ---------------- enc from stashed za/zb: z = alpha*(za-zb)+zb ------------
  const int split = coords[0];
  const bool policy = (chunk * CS) < split;
  float enc[REF];
#pragma unroll
  for (int q = 0; q < 4; ++q) {
    const ux4 p = *reinterpret_cast<const ux4*>(row + 4 * q);
#pragma unroll
    for (int m = 0; m < 4; ++m) {
      const float zav = blo(p[m]);
      const float zbv = bhi(p[m]);
      enc[4 * q + m] = fast_tanh(fmaf(alpha, zav - zbv, zbv));
    }
  }

  // ---------------- h[64] once -> bf16 pairs in LDS (overwrites zpk) --------
#pragma unroll 1
  for (int jo = 0; jo < 8; ++jo) {  // 8 h values per iter -> one b128 write
    float hv[8];
#pragma unroll
    for (int c = 0; c < 8; ++c) {
      const int j = jo * 8 + c;
      float acc = policy ? ws[4096 + j] : ws[4160 + j];
      const float* wc = ws + 3072 + j * REF;  // contiguous, wave-uniform
#pragma unroll
      for (int k = 0; k < REF; ++k) acc = fmaf(enc[k], wc[k], acc);
      hv[c] = fast_tanh(acc);
    }
    ux4 p;
#pragma unroll
    for (int m = 0; m < 4; ++m) p[m] = bpack2(hv[2 * m], hv[2 * m + 1]);
    *reinterpret_cast<ux4*>(row + 4 * jo) = p;
  }

  // ---------------- 4 strips of 16: corr from LDS h octets ------------------
  const float csv = policy ? cs_p[0] : cs_m[0];
  const float esv = policy ? es_p[0] : es_m[0];
  const float* np_ = noise + off;
  float* op = out + off;
#pragma unroll 1
  for (int s = 0; s < 4; ++s) {
    float corr[16];
#pragma unroll
    for (int ii = 0; ii < 16; ++ii) corr[ii] = b_c2[s * 16 + ii];
#pragma unroll 1
    for (int jo = 0; jo < 8; ++jo) {
      const ux4 p = *reinterpret_cast<const ux4*>(row + 4 * jo);
      float hf[8];
#pragma unroll
      for (int m = 0; m < 4; ++m) {
        hf[2 * m] = blo(p[m]);
        hf[2 * m + 1] = bhi(p[m]);
      }
      const float* w2 = ws + 4224 + (jo * 8) * HID + s * 16;  // uniform rows
#pragma unroll
      for (int c = 0; c < 8; ++c) {
#pragma unroll
        for (int ii = 0; ii < 16; ++ii)
          corr[ii] = fmaf(hf[c], w2[c * HID + ii], corr[ii]);
      }
    }
    // Strip epilogue: recompute base from (cache-hot) a,b; add corr + noise.
#pragma unroll
    for (int q = 0; q < 4; ++q) {
      const int i0 = s * 16 + 4 * q;
      const float4 a4 = *reinterpret_cast<const float4*>(ap + i0);
      const float4 b4 = *reinterpret_cast<const float4*>(bp + i0);
      const fx4 n4 = __builtin_nontemporal_load(
          reinterpret_cast<const fx4*>(np_ + i0));
      fx4 o;
#pragma unroll
      for (int c = 0; c < 4; ++c) {
        const float av = get4(a4, c);
        const float bv = get4(b4, c);
        const float bb = fmaf(alpha, av - bv, bv);
        float cv = fast_tanh(corr[4 * q + c]) * csv;
        cv = fminf(fmaxf(cv, -0.1f), 0.1f);
        o[c] = bb + cv + n4[c] * esv;
      }
      __builtin_nontemporal_store(o, reinterpret_cast<fx4*>(op + i0));
    }
  }
}

extern "C" void kernel_launch(void* const* d_in, const int* in_sizes, int n_in,
                              void* d_out, int out_size, void* d_ws, size_t ws_size,
                              hipStream_t stream) {
  const float* A     = (const float*)d_in[0];
  const float* B     = (const float*)d_in[1];
  const int*   coord = (const int*)d_in[2];
  const float* noise = (const float*)d_in[3];
  const float* w_enc = (const float*)d_in[4];
  const float* b_enc = (const float*)d_in[5];
  const float* w_c1  = (const float*)d_in[6];
  const float* b_c1  = (const float*)d_in[7];
  const float* w_c2  = (const float*)d_in[8];
  const float* b_c2  = (const float*)d_in[9];
  const float* w_g1  = (const float*)d_in[10];
  const float* b_g1  = (const float*)d_in[11];
  const float* w_g2  = (const float*)d_in[12];
  const float* b_g2  = (const float*)d_in[13];
  const float* ref_p = (const float*)d_in[14];
  const float* ref_m = (const float*)d_in[15];
  const float* cs_p  = (const float*)d_in[16];
  const float* cs_m  = (const float*)d_in[17];
  const float* es_p  = (const float*)d_in[18];
  const float* es_m  = (const float*)d_in[19];
  float* out = (float*)d_out;
  float* ws  = (float*)d_ws;

  setup_fold_kernel<<<1, 256, 0, stream>>>(w_g1, w_c1, b_c1, w_enc, w_c2,
                                           w_g2, b_g2, ref_p, ref_m, ws);

  const int blocks = NC / 256;
  dual_mutate_kernel<<<blocks, 256, 0, stream>>>(
      A, B, coord, noise, b_enc, b_c2, b_g1,
      cs_p, cs_m, es_p, es_m, ws, out);
}